// Round 12
// baseline (400.014 us; speedup 1.0000x reference)
//
#include <hip/hip_runtime.h>

// ---- filter / neuron constants (double, matching the Python reference) ----
#define EMD 0.8824969025845955      // exp(-1/8)
#define ESD 0.6065306597126334      // exp(-1/2)
#define A1C ((float)(EMD + ESD))                    // y[t-1] coeff
#define A2C ((float)(-(EMD * ESD)))                 // y[t-2] coeff
#define BC  ((float)((8.0 / 6.0) * (EMD - ESD)))    // x[t] coeff (ETA=8/6)
#define EMF ((float)EMD)                            // reset decay

// B=64, T=300. Layers: 300 -> 500 -> 200 -> 500 -> 300.
//
// Exactness contract (absmax 0.0 through r16): reference currents are a
// SEQUENTIAL ascending-i fp32 fold of W[o,i]*s[i]; spikes are exactly 0/1.
// Skipping s==0 terms is bitwise-neutral; set bits processed ascending is
// the SAME add sequence. Spikes travel as packed u32 masks (bit j of word w
// = neuron w*32+j); walk = ascending bits within word, words/chunks
// ascending -> identical fold per (t,o). Currents/outputs travel [B,O,T]
// (layout only; the per-(t,o) arithmetic sequence does not change).
//
// History (measured): r8 16KB+reg-staging+prefetch: spmm 77us. r9 s_load
// masks: regressed (SMEM shares lgkmcnt with DS, out-of-order). r10
// global_load_lds + scan-fusion: both regressed. r11: 475us. r12 OPL=4 with
// grid==LDS-cap: occ 24%. r13 OPL=4 + queue slack (2432 blocks/5-cap):
// spmm 73-77, occ 33-35 -- CONFIRMED OPTIMUM (r13/r15/r16). r14 NU=16:
// occ 13.7% -- parallelism dominates staging amortization. r16 layout
// inversion [B,O,T]: 462->385us (scans contiguous, output transposes
// deleted; spmm store epilogue free). r17: scan ring 16->32 t in flight
// (scans are latency-bound at <=2 waves/SIMD; depth 8 doubles cover);
// L4 spmm -> <4,4> (2 o-blocks instead of 3 -> per-bit visits 3->2).

// ---------------------------------------------------------------------------
// Merged prep: z 0..3 = weight transpose W[O,K] -> Wt[K,O]; z 4..67 =
// input transpose+pack for batch b = z-4 (src [300][300] floats -> masks
// M[b][t][kw], bit j of word kw = (src[b][kw*32+j][t] != 0)).
// Grid (16,16,68); pack blocks outside 10x10 exit early (block-uniform).
// ---------------------------------------------------------------------------
__global__ __launch_bounds__(256) void prep_all(
    const float* __restrict__ W1, float* __restrict__ D1,
    const float* __restrict__ W2, float* __restrict__ D2,
    const float* __restrict__ W3, float* __restrict__ D3,
    const float* __restrict__ W4, float* __restrict__ D4,
    const float* __restrict__ inp, unsigned* __restrict__ M)
{
    __shared__ float tile[32][33];
    const int z  = blockIdx.z;
    const int tx = threadIdx.x;           // 0..31
    const int ty = threadIdx.y;           // 0..7
    const int c0 = blockIdx.x * 32;
    const int r0 = blockIdx.y * 32;

    if (z < 4) {
        int R, C; const float* S; float* D;
        switch (z) {
            case 0:  S = W1; D = D1; R = 500; C = 300; break;
            case 1:  S = W2; D = D2; R = 200; C = 500; break;
            case 2:  S = W3; D = D3; R = 500; C = 200; break;
            default: S = W4; D = D4; R = 300; C = 500; break;
        }
        if (c0 >= C || r0 >= R) return;   // block-uniform, before barrier
#pragma unroll
        for (int s = 0; s < 4; s++) {
            const int r = r0 + ty + 8 * s;
            const int c = c0 + tx;
            if (r < R && c < C) tile[ty + 8 * s][tx] = S[(size_t)r * C + c];
        }
        __syncthreads();
#pragma unroll
        for (int s = 0; s < 4; s++) {
            const int c = c0 + ty + 8 * s;
            const int r = r0 + tx;
            if (c < C && r < R) D[(size_t)c * R + r] = tile[tx][ty + 8 * s];
        }
        return;
    }

    // ---- pack job: b = z - 4, R = C = 300, MW = 10
    if (c0 >= 300 || r0 >= 300) return;   // block-uniform, before barrier
    const int b = z - 4;
    const float* S = inp + (size_t)b * 90000;
#pragma unroll
    for (int s = 0; s < 4; s++) {
        const int r = r0 + ty + 8 * s;
        const int c = c0 + tx;
        tile[ty + 8 * s][tx] = (r < 300 && c < 300) ? S[(size_t)r * 300 + c] : 0.0f;
    }
    __syncthreads();
    const int wv   = ty >> 1;             // 0..3
    const int half = ty & 1;
#pragma unroll
    for (int s = 0; s < 4; s++) {
        const int tl = wv * 8 + s * 2 + half;          // 0..31, both halves
        const float v = tile[tx][tl];                  // OOB pre-zeroed
        const unsigned long long mb = __ballot(v != 0.0f);
        const int t = c0 + tl;
        if (tx == 0 && t < 300) {
            const unsigned w32 = half ? (unsigned)(mb >> 32) : (unsigned)mb;
            M[((size_t)b * 300 + t) * 10 + (r0 >> 5)] = w32;
        }
    }
}

// ---------------------------------------------------------------------------
// Sparse spike GEMM, templated (r13-proven configs), [B,O,T] output:
//   OPL = outputs per lane (2 -> float2/ds_read_b64, 4 -> float4/b128)
//   NU  = t-slots per wave (t-chunk = 4*NU); wave covers CONTIGUOUS t-run
//         twave = t0 + wv*NU; epilogue stores float4 t-runs at [o][twave+4q]
//         (same store-instruction count; the block's quarter-lines L2-merge).
// C[b,o,t] = sum_i Wt[i,o] * bit(M[b,t,i]), skipping zeros. KG fixed at 32.
// K staged in 32-row LDS chunks, weights register-prefetched one chunk
// ahead (r8 staging). Masks: per-lane-addressed VECTOR broadcast loads
// (vmcnt, not s_load/lgkmcnt); readfirstlane at walk time. Walk: scalar ctz
// on wave-uniform words, 4/2/1-wide groups, OPL adds per set-bit visit.
//   L1/L3 (O=500): <4,4>, grid (2,19,64) -- measured optimum (r13/r15/r16).
//   L4 (O=300): <4,4>, grid (2,19,64) -- 2 o-blocks instead of 3: per-bit
//     wave-visits 3->2 (r17; block 1 is 44/256 useful but walk work is
//     per-block, so net visits still drop).
//   L2 (O=200): <2,8>, 16 KB -- proven config (OPL=4 grid would sit at
//     4.75/5-cap = r12 trap).
// ---------------------------------------------------------------------------
template<int OPL> struct VecSel;
template<> struct VecSel<2> { using T = float2; };
template<> struct VecSel<4> { using T = float4; };

__device__ __forceinline__ void vzero(float2& a){ a.x=0.f; a.y=0.f; }
__device__ __forceinline__ void vzero(float4& a){ a.x=0.f; a.y=0.f; a.z=0.f; a.w=0.f; }
__device__ __forceinline__ void vaccum(float2& a, const float2 w){ a.x+=w.x; a.y+=w.y; }
__device__ __forceinline__ void vaccum(float4& a, const float4 w){ a.x+=w.x; a.y+=w.y; a.z+=w.z; a.w+=w.w; }
__device__ __forceinline__ float vget(const float2& a, int j){ return j == 0 ? a.x : a.y; }
__device__ __forceinline__ float vget(const float4& a, int j){
    return j == 0 ? a.x : (j == 1 ? a.y : (j == 2 ? a.z : a.w)); }

// walk one wave-uniform u32 mask word into one OPL-wide accumulator
#define WALK32(mw, accu, wl)                                                  \
    {                                                                         \
        unsigned mask_ = (mw);                                                \
        int n_ = __popc(mask_);                                               \
        while (n_ >= 4) {                                                     \
            const int j0_ = __builtin_ctz(mask_); mask_ &= mask_ - 1u;        \
            const int j1_ = __builtin_ctz(mask_); mask_ &= mask_ - 1u;        \
            const int j2_ = __builtin_ctz(mask_); mask_ &= mask_ - 1u;        \
            const int j3_ = __builtin_ctz(mask_); mask_ &= mask_ - 1u;        \
            const VT w0_ = *(const VT*)(&(wl)[j0_ * OCN]);                    \
            const VT w1_ = *(const VT*)(&(wl)[j1_ * OCN]);                    \
            const VT w2_ = *(const VT*)(&(wl)[j2_ * OCN]);                    \
            const VT w3_ = *(const VT*)(&(wl)[j3_ * OCN]);                    \
            vaccum(accu, w0_); vaccum(accu, w1_);                             \
            vaccum(accu, w2_); vaccum(accu, w3_);                             \
            n_ -= 4;                                                          \
        }                                                                     \
        if (n_ >= 2) {                                                        \
            const int j0_ = __builtin_ctz(mask_); mask_ &= mask_ - 1u;        \
            const int j1_ = __builtin_ctz(mask_); mask_ &= mask_ - 1u;        \
            const VT w0_ = *(const VT*)(&(wl)[j0_ * OCN]);                    \
            const VT w1_ = *(const VT*)(&(wl)[j1_ * OCN]);                    \
            vaccum(accu, w0_); vaccum(accu, w1_);                             \
            n_ -= 2;                                                          \
        }                                                                     \
        if (n_ > 0) {                                                         \
            const int j0_ = __builtin_ctz(mask_);                             \
            const VT w0_ = *(const VT*)(&(wl)[j0_ * OCN]);                    \
            vaccum(accu, w0_);                                                \
        }                                                                     \
    }

template<int OPL, int NU>
__global__ __launch_bounds__(256) void spmm_snn(
    const unsigned* __restrict__ M, const float* __restrict__ Wt,
    float* __restrict__ C, int K, int O, int T, int MW)
{
    constexpr int OCN = OPL * 64;
    constexpr int KG  = 32;
    constexpr int C4  = OCN / 4;          // float4 columns per row
    constexpr int NF4 = KG * OCN / 1024;  // float4s per thread per chunk
    using VT = typename VecSel<OPL>::T;
    __shared__ float Wls[KG * OCN];       // OPL=2: 16KB, OPL=4: 32KB
    const int tid  = threadIdx.x;
    const int lane = tid & 63;
    const int wv   = tid >> 6;            // 0..3 (per-lane -> vector loads)
    const int oc   = blockIdx.x * OCN;
    const int t0   = blockIdx.y * (NU * 4);
    const int b    = blockIdx.z;
    const int twave = t0 + wv * NU;       // wave's contiguous t-run

    const unsigned* Mb = M + (size_t)b * T * MW;
    float* Cb = C + (size_t)b * (size_t)O * T;    // [O][T]

    VT acc[NU];
#pragma unroll
    for (int u = 0; u < NU; u++) vzero(acc[u]);

    const int nkc = (K + KG - 1) / KG;
    float4 wpf[NF4];

#define LOADW(kc)                                                              \
    {                                                                          \
        const int kb_ = (kc) * KG;                                             \
        _Pragma("unroll")                                                      \
        for (int r = 0; r < NF4; r++) {                                        \
            const int idx = r * 256 + tid;                                     \
            const int k = kb_ + idx / C4;                                      \
            const int o = oc + (idx % C4) * 4;                                 \
            float4 w = make_float4(0.f, 0.f, 0.f, 0.f);                        \
            if (k < K && o + 3 < O)                                            \
                w = *reinterpret_cast<const float4*>(&Wt[(size_t)k * O + o]);  \
            wpf[r] = w;                                                        \
        }                                                                      \
    }

#define STOREW()                                                               \
    {                                                                          \
        _Pragma("unroll")                                                      \
        for (int r = 0; r < NF4; r++) {                                        \
            const int idx = r * 256 + tid;                                     \
            *reinterpret_cast<float4*>(                                        \
                &Wls[(idx / C4) * OCN + (idx % C4) * 4]) = wpf[r];             \
        }                                                                      \
    }

    // mask rows: per-lane (tid-derived) addresses -> VECTOR broadcast loads
    // on vmcnt. readfirstlane only at walk time. Invalid t clamps to row 0,
    // value masked to 0.
    const unsigned* mrow[NU];
    bool tvalid[NU];
#pragma unroll
    for (int u = 0; u < NU; u++) {
        const int t = twave + u;
        tvalid[u] = (t < T);
        mrow[u] = Mb + (size_t)(tvalid[u] ? t : 0) * MW;
    }

    unsigned mk[NU], mkn[NU];
#define LOADM(kc, dst)                                                         \
    {                                                                          \
        _Pragma("unroll")                                                      \
        for (int u = 0; u < NU; u++)                                           \
            dst[u] = tvalid[u] ? mrow[u][(kc)] : 0u;                           \
    }

    LOADW(0)
    LOADM(0, mk)
    STOREW()
    __syncthreads();

    // per-lane LDS base: row j's VT for this lane at float offset j*OCN
    const float* wl = &Wls[lane * OPL];

    for (int kc = 0; kc < nkc; kc++) {
        if (kc + 1 < nkc) {
            LOADW(kc + 1)          // global->reg, lands during the walk
            LOADM(kc + 1, mkn)
        }

#pragma unroll
        for (int u = 0; u < NU; u++) {
            const unsigned m_ = (unsigned)__builtin_amdgcn_readfirstlane(mk[u]);
            WALK32(m_, acc[u], wl)             // t = twave + u
        }

        if (kc + 1 < nkc) {
            __syncthreads();       // all waves done reading Wls
            STOREW()
#pragma unroll
            for (int u = 0; u < NU; u++) mk[u] = mkn[u];
            __syncthreads();       // Wls chunk kc+1 visible
        }
    }

    // ---- transposed store: per o-row, float4 t-runs (16B aligned:
    // row stride 1200B, twave%4==0). L2 merges the block's quarter-lines.
#pragma unroll
    for (int j = 0; j < OPL; j++) {
        const int o = oc + lane * OPL + j;
        if (o < O) {
            float* orow = Cb + (size_t)o * T;
#pragma unroll
            for (int q = 0; q < NU / 4; q++) {
                const int tq = twave + q * 4;
                if (tq < T) {                  // T%4==0 -> all-or-nothing
                    float4 v;
                    v.x = vget(acc[q * 4 + 0], j);
                    v.y = vget(acc[q * 4 + 1], j);
                    v.z = vget(acc[q * 4 + 2], j);
                    v.w = vget(acc[q * 4 + 3], j);
                    *reinterpret_cast<float4*>(orow + tq) = v;
                }
            }
        }
    }
#undef LOADW
#undef STOREW
#undef LOADM
}

// ---------------------------------------------------------------------------
// LIF (layers 1-3): currents C[b,o,t] (contiguous per-o rows) -> packed
// spike masks M[b][t][MW]. One wave per (b, 64-o-chunk). Float4 ring depth
// 8 (32 t's in flight; r16's depth 4 covered only ~160cy of ~600cy load
// latency at <=2 waves/SIMD). T = 9*32 + 12.
// ---------------------------------------------------------------------------
#define LIF_STEP_S(xval, sval)                                                 \
    {                                                                          \
        const float y = A1 * y1 + A2 * y2 + Bc * (xval); y2 = y1; y1 = y;      \
        const float v = y + bi + r;                                            \
        sval = (v >= 1.0f) ? 1.0f : 0.0f;                                      \
        r = r * EMF - sval;                                                    \
    }

#define F4E(v, e) ((e) == 0 ? (v).x : (e) == 1 ? (v).y : (e) == 2 ? (v).z : (v).w)

__global__ __launch_bounds__(64) void lif_pack(
    const float* __restrict__ C, unsigned* __restrict__ M,
    const float* __restrict__ bias,
    const float* __restrict__ a1p, const float* __restrict__ a2p,
    const float* __restrict__ bp, int O, int MW)
{
    const int lane = threadIdx.x;
    const int o = blockIdx.x * 64 + lane;
    const int b = blockIdx.y;
    if (o >= O) return;                    // exited lanes ballot as 0
    const float A1 = a1p[0], A2 = a2p[0], Bc = bp[0];
    const float bi = bias[o];
    const float4* r4 = (const float4*)(C + ((size_t)b * O + o) * 300);
    unsigned long long* Mp =
        (unsigned long long*)(M + (size_t)b * 300 * MW);
    const int pair = blockIdx.x;
    const int hw   = MW >> 1;

    float4 pf[8];                          // t .. t+31 in flight
#pragma unroll
    for (int i = 0; i < 8; i++) pf[i] = r4[i];

    float y1 = 0.f, y2 = 0.f, r = 0.f;
    for (int blk = 0; blk < 9; blk++) {    // t = 0..287
#pragma unroll
        for (int q = 0; q < 8; q++) {
            const float4 cur = pf[q];
            const int nt = blk * 32 + q * 4 + 32;
            if (nt < 300) pf[q] = r4[nt >> 2];
#pragma unroll
            for (int e = 0; e < 4; e++) {
                const int t = blk * 32 + q * 4 + e;
                const float x = F4E(cur, e);
                float s;
                LIF_STEP_S(x, s)
                const unsigned long long mb = __ballot(s != 0.0f);
                if (lane == 0) Mp[(size_t)t * hw + pair] = mb;
            }
        }
    }
#pragma unroll
    for (int q = 0; q < 3; q++) {          // t = 288..299
        const float4 cur = pf[q];
#pragma unroll
        for (int e = 0; e < 4; e++) {
            const int t = 288 + q * 4 + e;
            const float x = F4E(cur, e);
            float s;
            LIF_STEP_S(x, s)
            const unsigned long long mb = __ballot(s != 0.0f);
            if (lane == 0) Mp[(size_t)t * hw + pair] = mb;
        }
    }
}

// ---------------------------------------------------------------------------
// Layer-4 LIF + fixed output dual-exp IIR, all [B,O,T]: Cc currents in,
// S4 spikes out, F filtered out -- written DIRECTLY in final layout as
// buffered float4 t-runs. Float4 ring depth 8 as above.
// ---------------------------------------------------------------------------
__global__ __launch_bounds__(64) void lif4_t(
    const float* __restrict__ Cc, float* __restrict__ S4,
    float* __restrict__ F, const float* __restrict__ bias,
    const float* __restrict__ a1p, const float* __restrict__ a2p,
    const float* __restrict__ bp, int O)
{
    const int o = blockIdx.x * 64 + threadIdx.x;
    const int b = blockIdx.y;
    if (o >= O) return;
    const float A1 = a1p[0], A2 = a2p[0], Bc = bp[0];
    const float bi = bias[o];
    const float4* r4 = (const float4*)(Cc + ((size_t)b * O + o) * 300);
    float4* s4r = (float4*)(S4 + ((size_t)b * O + o) * 300);
    float4* f4r = (float4*)(F  + ((size_t)b * O + o) * 300);

    float4 pf[8];
#pragma unroll
    for (int i = 0; i < 8; i++) pf[i] = r4[i];

    float y1 = 0.f, y2 = 0.f, r = 0.f;
    float z1 = 0.f, z2 = 0.f;
    for (int blk = 0; blk < 9; blk++) {    // t = 0..287
#pragma unroll
        for (int q = 0; q < 8; q++) {
            const float4 cur = pf[q];
            const int nt = blk * 32 + q * 4 + 32;
            if (nt < 300) pf[q] = r4[nt >> 2];
            float sv[4], zv[4];
#pragma unroll
            for (int e = 0; e < 4; e++) {  // e compile-time -> regs
                const float x = F4E(cur, e);
                float s;
                LIF_STEP_S(x, s)
                const float z = A1C * z1 + A2C * z2 + BC * s; z2 = z1; z1 = z;
                sv[e] = s; zv[e] = z;
            }
            const int fi = (blk * 32 + q * 4) >> 2;
            s4r[fi] = make_float4(sv[0], sv[1], sv[2], sv[3]);
            f4r[fi] = make_float4(zv[0], zv[1], zv[2], zv[3]);
        }
    }
#pragma unroll
    for (int q = 0; q < 3; q++) {          // t = 288..299
        const float4 cur = pf[q];
        float sv[4], zv[4];
#pragma unroll
        for (int e = 0; e < 4; e++) {
            const float x = F4E(cur, e);
            float s;
            LIF_STEP_S(x, s)
            const float z = A1C * z1 + A2C * z2 + BC * s; z2 = z1; z1 = z;
            sv[e] = s; zv[e] = z;
        }
        const int fi = (288 + q * 4) >> 2;
        s4r[fi] = make_float4(sv[0], sv[1], sv[2], sv[3]);
        f4r[fi] = make_float4(zv[0], zv[1], zv[2], zv[3]);
    }
}

// ---------------------------------------------------------------------------
extern "C" void kernel_launch(void* const* d_in, const int* in_sizes, int n_in,
                              void* d_out, int out_size, void* d_ws, size_t ws_size,
                              hipStream_t stream)
{
    const float* inputs = (const float*)d_in[0];           // [64,300,300] binary
    const float* a1_1 = (const float*)d_in[1];
    const float* a2_1 = (const float*)d_in[2];
    const float* b_1  = (const float*)d_in[3];
    const float* W1   = (const float*)d_in[4];             // [500,300]
    const float* bias1= (const float*)d_in[5];
    const float* a1_2 = (const float*)d_in[6];
    const float* a2_2 = (const float*)d_in[7];
    const float* b_2  = (const float*)d_in[8];
    const float* W2   = (const float*)d_in[9];             // [200,500]
    const float* bias2= (const float*)d_in[10];
    const float* a1_3 = (const float*)d_in[11];
    const float* a2_3 = (const float*)d_in[12];
    const float* b_3  = (const float*)d_in[13];
    const float* W3   = (const float*)d_in[14];            // [500,200]
    const float* bias3= (const float*)d_in[15];
    const float* a1_4 = (const float*)d_in[16];
    const float* a2_4 = (const float*)d_in[17];
    const float* b_4  = (const float*)d_in[18];
    const float* W4   = (const float*)d_in[19];            // [300,500]
    const float* bias4= (const float*)d_in[20];

    const int B = 64, T = 300;

    // Workspace (13.44M floats), all currents in [B,O,T]:
    // c1 [B,500,300]=9.6M (L1, then L3, then L4 [B,300,300] reuse),
    // c2 [B,200,300]=3.84M (L2).
    float* ws = (float*)d_ws;
    float* c1 = ws;
    float* c2 = ws + 9600000;

    // d_out: region1 [0..5.76M) = Wt1..4 + masks (scratch), later final s4
    // [B,300,T] written DIRECTLY by lif4_t; region2 [5.76M..11.52M) = filt.
    float* out = (float*)d_out;
    float* reg1 = out;
    float* reg2 = out + 5760000;
    float* Wt1 = reg1;              // [300,500] = 150000
    float* Wt2 = reg1 + 150000;     // [500,200] = 100000
    float* Wt3 = reg1 + 250000;     // [200,500] = 100000
    float* Wt4 = reg1 + 350000;     // [500,300] = 150000
    // masks (u32), 8B-aligned, all dead before lif4_t overwrites reg1:
    unsigned* m0 = (unsigned*)(reg1 + 500000);   // [64,300,10] = 192000
    unsigned* m1 = (unsigned*)(reg1 + 692000);   // [64,300,16] = 307200
    unsigned* m2 = (unsigned*)(reg1 + 999200);   // [64,300, 8] = 153600
    unsigned* m3 = (unsigned*)(reg1 + 1152800);  // [64,300,16] = 307200

    const dim3 tb(32, 8);

    // Head: weight transposes + input transpose-pack in ONE launch
    prep_all<<<dim3(16, 16, 68), tb, 0, stream>>>(W1, Wt1, W2, Wt2,
                                                  W3, Wt3, W4, Wt4,
                                                  inputs, m0);

    // Layer 1: 300 -> 500   (OPL=4, TCN=16, r13 optimum; output [B,500,300])
    spmm_snn<4, 4><<<dim3(2, 19, B), 256, 0, stream>>>(m0, Wt1, c1, 300, 500, T, 10);
    lif_pack<<<dim3(8, B), 64, 0, stream>>>(c1, m1, bias1, a1_1, a2_1, b_1, 500, 16);
    // Layer 2: 500 -> 200   (OPL=2, 16KB; output [B,200,300])
    spmm_snn<2, 8><<<dim3(2, 10, B), 256, 0, stream>>>(m1, Wt2, c2, 500, 200, T, 16);
    lif_pack<<<dim3(4, B), 64, 0, stream>>>(c2, m2, bias2, a1_2, a2_2, b_2, 200, 8);
    // Layer 3: 200 -> 500   (back into c1)
    spmm_snn<4, 4><<<dim3(2, 19, B), 256, 0, stream>>>(m2, Wt3, c1, 200, 500, T, 8);
    lif_pack<<<dim3(8, B), 64, 0, stream>>>(c1, m3, bias3, a1_3, a2_3, b_3, 500, 16);
    // Layer 4: 500 -> 300   (r17: OPL=4 -> 2 o-blocks, per-bit visits 3->2;
    // currents [B,300,300] into c1, L3 currents dead)
    spmm_snn<4, 4><<<dim3(2, 19, B), 256, 0, stream>>>(m3, Wt4, c1, 500, 300, T, 16);
    // LIF+filter, final layout direct: s4 -> reg1, filt -> reg2.
    // (reg1's Wt/masks are dead once the L4 spmm above has completed.)
    lif4_t<<<dim3(5, B), 64, 0, stream>>>(c1, reg1, reg2, bias4, a1_4, a2_4, b_4, 300);
}

// Round 13
// 384.542 us; speedup vs baseline: 1.0402x; 1.0402x over previous
//
#include <hip/hip_runtime.h>

// ---- filter / neuron constants (double, matching the Python reference) ----
#define EMD 0.8824969025845955      // exp(-1/8)
#define ESD 0.6065306597126334      // exp(-1/2)
#define A1C ((float)(EMD + ESD))                    // y[t-1] coeff
#define A2C ((float)(-(EMD * ESD)))                 // y[t-2] coeff
#define BC  ((float)((8.0 / 6.0) * (EMD - ESD)))    // x[t] coeff (ETA=8/6)
#define EMF ((float)EMD)                            // reset decay

// B=64, T=300. Layers: 300 -> 500 -> 200 -> 500 -> 300.
//
// Exactness contract (absmax 0.0 through r17): reference currents are a
// SEQUENTIAL ascending-i fp32 fold of W[o,i]*s[i]; spikes are exactly 0/1.
// Skipping s==0 terms is bitwise-neutral; set bits processed ascending is
// the SAME add sequence. Spikes travel as packed u32 masks (bit j of word w
// = neuron w*32+j); walk = ascending bits within word, words/chunks
// ascending -> identical fold per (t,o). Currents/outputs travel [B,O,T]
// (layout only; the per-(t,o) arithmetic sequence does not change).
//
// History (measured): r8 16KB+reg-staging+prefetch: spmm 77us. r9 s_load
// masks: regressed (SMEM shares lgkmcnt with DS, out-of-order). r10
// global_load_lds + scan-fusion: both regressed. r11: 475us. r12 OPL=4 with
// grid==LDS-cap: occ 24%. r13 OPL=4 + queue slack: spmm 73-77, occ 33-35 --
// CONFIRMED OPTIMUM (r13/r15/r16). r14 NU=16: occ 13.7% -- parallelism
// dominates staging amortization. r16 layout inversion [B,O,T]: 462->385.5us
// BEST (scans contiguous, output transposes deleted; spmm store free).
// r17 regressed to 400: L4 <4,4> raises LDS bytes/bit 24->32B for O=300
// (OPL=4 only breaks even when o-block count conserves bytes, i.e. O=500);
// scan ring depth 8 neutral-at-best. r18 = r16 exact restore.

// ---------------------------------------------------------------------------
// Merged prep: z 0..3 = weight transpose W[O,K] -> Wt[K,O]; z 4..67 =
// input transpose+pack for batch b = z-4 (src [300][300] floats -> masks
// M[b][t][kw], bit j of word kw = (src[b][kw*32+j][t] != 0)).
// Grid (16,16,68); pack blocks outside 10x10 exit early (block-uniform).
// ---------------------------------------------------------------------------
__global__ __launch_bounds__(256) void prep_all(
    const float* __restrict__ W1, float* __restrict__ D1,
    const float* __restrict__ W2, float* __restrict__ D2,
    const float* __restrict__ W3, float* __restrict__ D3,
    const float* __restrict__ W4, float* __restrict__ D4,
    const float* __restrict__ inp, unsigned* __restrict__ M)
{
    __shared__ float tile[32][33];
    const int z  = blockIdx.z;
    const int tx = threadIdx.x;           // 0..31
    const int ty = threadIdx.y;           // 0..7
    const int c0 = blockIdx.x * 32;
    const int r0 = blockIdx.y * 32;

    if (z < 4) {
        int R, C; const float* S; float* D;
        switch (z) {
            case 0:  S = W1; D = D1; R = 500; C = 300; break;
            case 1:  S = W2; D = D2; R = 200; C = 500; break;
            case 2:  S = W3; D = D3; R = 500; C = 200; break;
            default: S = W4; D = D4; R = 300; C = 500; break;
        }
        if (c0 >= C || r0 >= R) return;   // block-uniform, before barrier
#pragma unroll
        for (int s = 0; s < 4; s++) {
            const int r = r0 + ty + 8 * s;
            const int c = c0 + tx;
            if (r < R && c < C) tile[ty + 8 * s][tx] = S[(size_t)r * C + c];
        }
        __syncthreads();
#pragma unroll
        for (int s = 0; s < 4; s++) {
            const int c = c0 + ty + 8 * s;
            const int r = r0 + tx;
            if (c < C && r < R) D[(size_t)c * R + r] = tile[tx][ty + 8 * s];
        }
        return;
    }

    // ---- pack job: b = z - 4, R = C = 300, MW = 10
    if (c0 >= 300 || r0 >= 300) return;   // block-uniform, before barrier
    const int b = z - 4;
    const float* S = inp + (size_t)b * 90000;
#pragma unroll
    for (int s = 0; s < 4; s++) {
        const int r = r0 + ty + 8 * s;
        const int c = c0 + tx;
        tile[ty + 8 * s][tx] = (r < 300 && c < 300) ? S[(size_t)r * 300 + c] : 0.0f;
    }
    __syncthreads();
    const int wv   = ty >> 1;             // 0..3
    const int half = ty & 1;
#pragma unroll
    for (int s = 0; s < 4; s++) {
        const int tl = wv * 8 + s * 2 + half;          // 0..31, both halves
        const float v = tile[tx][tl];                  // OOB pre-zeroed
        const unsigned long long mb = __ballot(v != 0.0f);
        const int t = c0 + tl;
        if (tx == 0 && t < 300) {
            const unsigned w32 = half ? (unsigned)(mb >> 32) : (unsigned)mb;
            M[((size_t)b * 300 + t) * 10 + (r0 >> 5)] = w32;
        }
    }
}

// ---------------------------------------------------------------------------
// Sparse spike GEMM, templated (r13-proven configs), [B,O,T] output:
//   OPL = outputs per lane (2 -> float2/ds_read_b64, 4 -> float4/b128)
//   NU  = t-slots per wave (t-chunk = 4*NU); wave covers CONTIGUOUS t-run
//         twave = t0 + wv*NU; epilogue stores float4 t-runs at [o][twave+4q]
//         (same store-instruction count; the block's quarter-lines L2-merge).
// C[b,o,t] = sum_i Wt[i,o] * bit(M[b,t,i]), skipping zeros. KG fixed at 32.
// K staged in 32-row LDS chunks, weights register-prefetched one chunk
// ahead (r8 staging). Masks: per-lane-addressed VECTOR broadcast loads
// (vmcnt, not s_load/lgkmcnt); readfirstlane at walk time. Walk: scalar ctz
// on wave-uniform words, 4/2/1-wide groups, OPL adds per set-bit visit.
//   L1/L3 (O=500): <4,4>, grid (2,19,64) -- measured optimum (r13/r15/r16);
//     LDS bytes/bit conserved (2 blocks x 16B == 4 blocks x 8B).
//   L2 (O=200) / L4 (O=300): <2,8>, 16 KB -- proven config. OPL=4 would
//     RAISE LDS bytes/bit for these O (r17: L4 24->32B, +15us total).
// ---------------------------------------------------------------------------
template<int OPL> struct VecSel;
template<> struct VecSel<2> { using T = float2; };
template<> struct VecSel<4> { using T = float4; };

__device__ __forceinline__ void vzero(float2& a){ a.x=0.f; a.y=0.f; }
__device__ __forceinline__ void vzero(float4& a){ a.x=0.f; a.y=0.f; a.z=0.f; a.w=0.f; }
__device__ __forceinline__ void vaccum(float2& a, const float2 w){ a.x+=w.x; a.y+=w.y; }
__device__ __forceinline__ void vaccum(float4& a, const float4 w){ a.x+=w.x; a.y+=w.y; a.z+=w.z; a.w+=w.w; }
__device__ __forceinline__ float vget(const float2& a, int j){ return j == 0 ? a.x : a.y; }
__device__ __forceinline__ float vget(const float4& a, int j){
    return j == 0 ? a.x : (j == 1 ? a.y : (j == 2 ? a.z : a.w)); }

// walk one wave-uniform u32 mask word into one OPL-wide accumulator
#define WALK32(mw, accu, wl)                                                  \
    {                                                                         \
        unsigned mask_ = (mw);                                                \
        int n_ = __popc(mask_);                                               \
        while (n_ >= 4) {                                                     \
            const int j0_ = __builtin_ctz(mask_); mask_ &= mask_ - 1u;        \
            const int j1_ = __builtin_ctz(mask_); mask_ &= mask_ - 1u;        \
            const int j2_ = __builtin_ctz(mask_); mask_ &= mask_ - 1u;        \
            const int j3_ = __builtin_ctz(mask_); mask_ &= mask_ - 1u;        \
            const VT w0_ = *(const VT*)(&(wl)[j0_ * OCN]);                    \
            const VT w1_ = *(const VT*)(&(wl)[j1_ * OCN]);                    \
            const VT w2_ = *(const VT*)(&(wl)[j2_ * OCN]);                    \
            const VT w3_ = *(const VT*)(&(wl)[j3_ * OCN]);                    \
            vaccum(accu, w0_); vaccum(accu, w1_);                             \
            vaccum(accu, w2_); vaccum(accu, w3_);                             \
            n_ -= 4;                                                          \
        }                                                                     \
        if (n_ >= 2) {                                                        \
            const int j0_ = __builtin_ctz(mask_); mask_ &= mask_ - 1u;        \
            const int j1_ = __builtin_ctz(mask_); mask_ &= mask_ - 1u;        \
            const VT w0_ = *(const VT*)(&(wl)[j0_ * OCN]);                    \
            const VT w1_ = *(const VT*)(&(wl)[j1_ * OCN]);                    \
            vaccum(accu, w0_); vaccum(accu, w1_);                             \
            n_ -= 2;                                                          \
        }                                                                     \
        if (n_ > 0) {                                                         \
            const int j0_ = __builtin_ctz(mask_);                             \
            const VT w0_ = *(const VT*)(&(wl)[j0_ * OCN]);                    \
            vaccum(accu, w0_);                                                \
        }                                                                     \
    }

template<int OPL, int NU>
__global__ __launch_bounds__(256) void spmm_snn(
    const unsigned* __restrict__ M, const float* __restrict__ Wt,
    float* __restrict__ C, int K, int O, int T, int MW)
{
    constexpr int OCN = OPL * 64;
    constexpr int KG  = 32;
    constexpr int C4  = OCN / 4;          // float4 columns per row
    constexpr int NF4 = KG * OCN / 1024;  // float4s per thread per chunk
    using VT = typename VecSel<OPL>::T;
    __shared__ float Wls[KG * OCN];       // OPL=2: 16KB, OPL=4: 32KB
    const int tid  = threadIdx.x;
    const int lane = tid & 63;
    const int wv   = tid >> 6;            // 0..3 (per-lane -> vector loads)
    const int oc   = blockIdx.x * OCN;
    const int t0   = blockIdx.y * (NU * 4);
    const int b    = blockIdx.z;
    const int twave = t0 + wv * NU;       // wave's contiguous t-run

    const unsigned* Mb = M + (size_t)b * T * MW;
    float* Cb = C + (size_t)b * (size_t)O * T;    // [O][T]

    VT acc[NU];
#pragma unroll
    for (int u = 0; u < NU; u++) vzero(acc[u]);

    const int nkc = (K + KG - 1) / KG;
    float4 wpf[NF4];

#define LOADW(kc)                                                              \
    {                                                                          \
        const int kb_ = (kc) * KG;                                             \
        _Pragma("unroll")                                                      \
        for (int r = 0; r < NF4; r++) {                                        \
            const int idx = r * 256 + tid;                                     \
            const int k = kb_ + idx / C4;                                      \
            const int o = oc + (idx % C4) * 4;                                 \
            float4 w = make_float4(0.f, 0.f, 0.f, 0.f);                        \
            if (k < K && o + 3 < O)                                            \
                w = *reinterpret_cast<const float4*>(&Wt[(size_t)k * O + o]);  \
            wpf[r] = w;                                                        \
        }                                                                      \
    }

#define STOREW()                                                               \
    {                                                                          \
        _Pragma("unroll")                                                      \
        for (int r = 0; r < NF4; r++) {                                        \
            const int idx = r * 256 + tid;                                     \
            *reinterpret_cast<float4*>(                                        \
                &Wls[(idx / C4) * OCN + (idx % C4) * 4]) = wpf[r];             \
        }                                                                      \
    }

    // mask rows: per-lane (tid-derived) addresses -> VECTOR broadcast loads
    // on vmcnt. readfirstlane only at walk time. Invalid t clamps to row 0,
    // value masked to 0.
    const unsigned* mrow[NU];
    bool tvalid[NU];
#pragma unroll
    for (int u = 0; u < NU; u++) {
        const int t = twave + u;
        tvalid[u] = (t < T);
        mrow[u] = Mb + (size_t)(tvalid[u] ? t : 0) * MW;
    }

    unsigned mk[NU], mkn[NU];
#define LOADM(kc, dst)                                                         \
    {                                                                          \
        _Pragma("unroll")                                                      \
        for (int u = 0; u < NU; u++)                                           \
            dst[u] = tvalid[u] ? mrow[u][(kc)] : 0u;                           \
    }

    LOADW(0)
    LOADM(0, mk)
    STOREW()
    __syncthreads();

    // per-lane LDS base: row j's VT for this lane at float offset j*OCN
    const float* wl = &Wls[lane * OPL];

    for (int kc = 0; kc < nkc; kc++) {
        if (kc + 1 < nkc) {
            LOADW(kc + 1)          // global->reg, lands during the walk
            LOADM(kc + 1, mkn)
        }

#pragma unroll
        for (int u = 0; u < NU; u++) {
            const unsigned m_ = (unsigned)__builtin_amdgcn_readfirstlane(mk[u]);
            WALK32(m_, acc[u], wl)             // t = twave + u
        }

        if (kc + 1 < nkc) {
            __syncthreads();       // all waves done reading Wls
            STOREW()
#pragma unroll
            for (int u = 0; u < NU; u++) mk[u] = mkn[u];
            __syncthreads();       // Wls chunk kc+1 visible
        }
    }

    // ---- transposed store: per o-row, float4 t-runs (16B aligned:
    // row stride 1200B, twave%4==0). L2 merges the block's quarter-lines.
#pragma unroll
    for (int j = 0; j < OPL; j++) {
        const int o = oc + lane * OPL + j;
        if (o < O) {
            float* orow = Cb + (size_t)o * T;
#pragma unroll
            for (int q = 0; q < NU / 4; q++) {
                const int tq = twave + q * 4;
                if (tq < T) {                  // T%4==0 -> all-or-nothing
                    float4 v;
                    v.x = vget(acc[q * 4 + 0], j);
                    v.y = vget(acc[q * 4 + 1], j);
                    v.z = vget(acc[q * 4 + 2], j);
                    v.w = vget(acc[q * 4 + 3], j);
                    *reinterpret_cast<float4*>(orow + tq) = v;
                }
            }
        }
    }
#undef LOADW
#undef STOREW
#undef LOADM
}

// ---------------------------------------------------------------------------
// LIF (layers 1-3): currents C[b,o,t] (contiguous per-o rows) -> packed
// spike masks M[b][t][MW]. One wave per (b, 64-o-chunk); float4 ring over
// t (16 t's in flight -- r16 proven; depth 8 was neutral-at-best in r17);
// per t: LIF step + __ballot -> one 8B store from lane 0.
// ---------------------------------------------------------------------------
#define LIF_STEP_S(xval, sval)                                                 \
    {                                                                          \
        const float y = A1 * y1 + A2 * y2 + Bc * (xval); y2 = y1; y1 = y;      \
        const float v = y + bi + r;                                            \
        sval = (v >= 1.0f) ? 1.0f : 0.0f;                                      \
        r = r * EMF - sval;                                                    \
    }

#define F4E(v, e) ((e) == 0 ? (v).x : (e) == 1 ? (v).y : (e) == 2 ? (v).z : (v).w)

__global__ __launch_bounds__(64) void lif_pack(
    const float* __restrict__ C, unsigned* __restrict__ M,
    const float* __restrict__ bias,
    const float* __restrict__ a1p, const float* __restrict__ a2p,
    const float* __restrict__ bp, int O, int MW)
{
    const int lane = threadIdx.x;
    const int o = blockIdx.x * 64 + lane;
    const int b = blockIdx.y;
    if (o >= O) return;                    // exited lanes ballot as 0
    const float A1 = a1p[0], A2 = a2p[0], Bc = bp[0];
    const float bi = bias[o];
    const float4* r4 = (const float4*)(C + ((size_t)b * O + o) * 300);
    unsigned long long* Mp =
        (unsigned long long*)(M + (size_t)b * 300 * MW);
    const int pair = blockIdx.x;
    const int hw   = MW >> 1;

    float4 pf[4];                          // t .. t+15 in flight
#pragma unroll
    for (int i = 0; i < 4; i++) pf[i] = r4[i];

    float y1 = 0.f, y2 = 0.f, r = 0.f;
    for (int blk = 0; blk < 18; blk++) {   // t = 0..287
#pragma unroll
        for (int q = 0; q < 4; q++) {
            const float4 cur = pf[q];
            const int nt = blk * 16 + q * 4 + 16;
            if (nt < 300) pf[q] = r4[nt >> 2];
#pragma unroll
            for (int e = 0; e < 4; e++) {
                const int t = blk * 16 + q * 4 + e;
                const float x = F4E(cur, e);
                float s;
                LIF_STEP_S(x, s)
                const unsigned long long mb = __ballot(s != 0.0f);
                if (lane == 0) Mp[(size_t)t * hw + pair] = mb;
            }
        }
    }
#pragma unroll
    for (int q = 0; q < 3; q++) {          // t = 288..299
        const float4 cur = pf[q];
#pragma unroll
        for (int e = 0; e < 4; e++) {
            const int t = 288 + q * 4 + e;
            const float x = F4E(cur, e);
            float s;
            LIF_STEP_S(x, s)
            const unsigned long long mb = __ballot(s != 0.0f);
            if (lane == 0) Mp[(size_t)t * hw + pair] = mb;
        }
    }
}

// ---------------------------------------------------------------------------
// Layer-4 LIF + fixed output dual-exp IIR, all [B,O,T]: Cc currents in,
// S4 spikes out, F filtered out -- written DIRECTLY in final layout as
// buffered float4 t-runs (contiguous per-thread rows). Float4 ring depth 4.
// ---------------------------------------------------------------------------
__global__ __launch_bounds__(64) void lif4_t(
    const float* __restrict__ Cc, float* __restrict__ S4,
    float* __restrict__ F, const float* __restrict__ bias,
    const float* __restrict__ a1p, const float* __restrict__ a2p,
    const float* __restrict__ bp, int O)
{
    const int o = blockIdx.x * 64 + threadIdx.x;
    const int b = blockIdx.y;
    if (o >= O) return;
    const float A1 = a1p[0], A2 = a2p[0], Bc = bp[0];
    const float bi = bias[o];
    const float4* r4 = (const float4*)(Cc + ((size_t)b * O + o) * 300);
    float4* s4r = (float4*)(S4 + ((size_t)b * O + o) * 300);
    float4* f4r = (float4*)(F  + ((size_t)b * O + o) * 300);

    float4 pf[4];
#pragma unroll
    for (int i = 0; i < 4; i++) pf[i] = r4[i];

    float y1 = 0.f, y2 = 0.f, r = 0.f;
    float z1 = 0.f, z2 = 0.f;
    for (int blk = 0; blk < 18; blk++) {   // t = 0..287
#pragma unroll
        for (int q = 0; q < 4; q++) {
            const float4 cur = pf[q];
            const int nt = blk * 16 + q * 4 + 16;
            if (nt < 300) pf[q] = r4[nt >> 2];
            float sv[4], zv[4];
#pragma unroll
            for (int e = 0; e < 4; e++) {  // e compile-time -> regs
                const float x = F4E(cur, e);
                float s;
                LIF_STEP_S(x, s)
                const float z = A1C * z1 + A2C * z2 + BC * s; z2 = z1; z1 = z;
                sv[e] = s; zv[e] = z;
            }
            const int fi = (blk * 16 + q * 4) >> 2;
            s4r[fi] = make_float4(sv[0], sv[1], sv[2], sv[3]);
            f4r[fi] = make_float4(zv[0], zv[1], zv[2], zv[3]);
        }
    }
#pragma unroll
    for (int q = 0; q < 3; q++) {          // t = 288..299
        const float4 cur = pf[q];
        float sv[4], zv[4];
#pragma unroll
        for (int e = 0; e < 4; e++) {
            const float x = F4E(cur, e);
            float s;
            LIF_STEP_S(x, s)
            const float z = A1C * z1 + A2C * z2 + BC * s; z2 = z1; z1 = z;
            sv[e] = s; zv[e] = z;
        }
        const int fi = (288 + q * 4) >> 2;
        s4r[fi] = make_float4(sv[0], sv[1], sv[2], sv[3]);
        f4r[fi] = make_float4(zv[0], zv[1], zv[2], zv[3]);
    }
}

// ---------------------------------------------------------------------------
extern "C" void kernel_launch(void* const* d_in, const int* in_sizes, int n_in,
                              void* d_out, int out_size, void* d_ws, size_t ws_size,
                              hipStream_t stream)
{
    const float* inputs = (const float*)d_in[0];           // [64,300,300] binary
    const float* a1_1 = (const float*)d_in[1];
    const float* a2_1 = (const float*)d_in[2];
    const float* b_1  = (const float*)d_in[3];
    const float* W1   = (const float*)d_in[4];             // [500,300]
    const float* bias1= (const float*)d_in[5];
    const float* a1_2 = (const float*)d_in[6];
    const float* a2_2 = (const float*)d_in[7];
    const float* b_2  = (const float*)d_in[8];
    const float* W2   = (const float*)d_in[9];             // [200,500]
    const float* bias2= (const float*)d_in[10];
    const float* a1_3 = (const float*)d_in[11];
    const float* a2_3 = (const float*)d_in[12];
    const float* b_3  = (const float*)d_in[13];
    const float* W3   = (const float*)d_in[14];            // [500,200]
    const float* bias3= (const float*)d_in[15];
    const float* a1_4 = (const float*)d_in[16];
    const float* a2_4 = (const float*)d_in[17];
    const float* b_4  = (const float*)d_in[18];
    const float* W4   = (const float*)d_in[19];            // [300,500]
    const float* bias4= (const float*)d_in[20];

    const int B = 64, T = 300;

    // Workspace (13.44M floats), all currents in [B,O,T]:
    // c1 [B,500,300]=9.6M (L1, then L3, then L4 [B,300,300] reuse),
    // c2 [B,200,300]=3.84M (L2).
    float* ws = (float*)d_ws;
    float* c1 = ws;
    float* c2 = ws + 9600000;

    // d_out: region1 [0..5.76M) = Wt1..4 + masks (scratch), later final s4
    // [B,300,T] written DIRECTLY by lif4_t; region2 [5.76M..11.52M) = filt.
    float* out = (float*)d_out;
    float* reg1 = out;
    float* reg2 = out + 5760000;
    float* Wt1 = reg1;              // [300,500] = 150000
    float* Wt2 = reg1 + 150000;     // [500,200] = 100000
    float* Wt3 = reg1 + 250000;     // [200,500] = 100000
    float* Wt4 = reg1 + 350000;     // [500,300] = 150000
    // masks (u32), 8B-aligned, all dead before lif4_t overwrites reg1:
    unsigned* m0 = (unsigned*)(reg1 + 500000);   // [64,300,10] = 192000
    unsigned* m1 = (unsigned*)(reg1 + 692000);   // [64,300,16] = 307200
    unsigned* m2 = (unsigned*)(reg1 + 999200);   // [64,300, 8] = 153600
    unsigned* m3 = (unsigned*)(reg1 + 1152800);  // [64,300,16] = 307200

    const dim3 tb(32, 8);

    // Head: weight transposes + input transpose-pack in ONE launch
    prep_all<<<dim3(16, 16, 68), tb, 0, stream>>>(W1, Wt1, W2, Wt2,
                                                  W3, Wt3, W4, Wt4,
                                                  inputs, m0);

    // Layer 1: 300 -> 500   (OPL=4, TCN=16, r13 optimum; output [B,500,300])
    spmm_snn<4, 4><<<dim3(2, 19, B), 256, 0, stream>>>(m0, Wt1, c1, 300, 500, T, 10);
    lif_pack<<<dim3(8, B), 64, 0, stream>>>(c1, m1, bias1, a1_1, a2_1, b_1, 500, 16);
    // Layer 2: 500 -> 200   (OPL=2, 16KB; output [B,200,300])
    spmm_snn<2, 8><<<dim3(2, 10, B), 256, 0, stream>>>(m1, Wt2, c2, 500, 200, T, 16);
    lif_pack<<<dim3(4, B), 64, 0, stream>>>(c2, m2, bias2, a1_2, a2_2, b_2, 200, 8);
    // Layer 3: 200 -> 500   (back into c1)
    spmm_snn<4, 4><<<dim3(2, 19, B), 256, 0, stream>>>(m2, Wt3, c1, 200, 500, T, 8);
    lif_pack<<<dim3(8, B), 64, 0, stream>>>(c1, m3, bias3, a1_3, a2_3, b_3, 500, 16);
    // Layer 4: 500 -> 300   (OPL=2, 16KB; currents [B,300,300] into c1)
    spmm_snn<2, 8><<<dim3(3, 10, B), 256, 0, stream>>>(m3, Wt4, c1, 500, 300, T, 16);
    // LIF+filter, final layout direct: s4 -> reg1, filt -> reg2.
    // (reg1's Wt/masks are dead once the L4 spmm above has completed.)
    lif4_t<<<dim3(5, B), 64, 0, stream>>>(c1, reg1, reg2, bias4, a1_4, a2_4, b_4, 300);
}